// Round 5
// baseline (157.882 us; speedup 1.0000x reference)
//
#include <hip/hip_runtime.h>

#define BB 8
#define SS 2048
#define DD 128

typedef _Float16 f16;
typedef _Float16 f16x2 __attribute__((ext_vector_type(2)));
typedef __fp16 h16x2 __attribute__((ext_vector_type(2)));
typedef _Float16 f16x8 __attribute__((ext_vector_type(8)));
typedef float f32x4 __attribute__((ext_vector_type(4)));

// Vt LDS swizzle: spreads banks for staging writes and PV reads.
#define SWV(d) ((((d) & 7) ^ (((d) >> 3) & 7)) << 3)

static __device__ __forceinline__ float fast_exp2(float x) {
#if __has_builtin(__builtin_amdgcn_exp2f)
    return __builtin_amdgcn_exp2f(x);
#else
    return exp2f(x);
#endif
}

static __device__ __forceinline__ f16x2 cvt_pk(float a, float b) {
    h16x2 r = __builtin_amdgcn_cvt_pkrtz(a, b);
    return __builtin_bit_cast(f16x2, r);
}

// pack 4 f32 -> 4 f16 (RTZ) as uint2 for one b64 LDS write
static __device__ __forceinline__ uint2 pack4(f32x4 v) {
    f16x2 lo = cvt_pk(v[0], v[1]);
    f16x2 hi = cvt_pk(v[2], v[3]);
    uint2 u;
    u.x = __builtin_bit_cast(unsigned int, lo);
    u.y = __builtin_bit_cast(unsigned int, hi);
    return u;
}

// ---------------------------------------------------------------------------
// Flash attention forward, causal. f16 MFMA 16x16x32, fp32 softmax/accum.
// 256 threads = 4 waves; each wave owns 32 q rows as TWO 16-row tiles
// (rt=0,1 at +0/+64), sharing every K/V B-fragment read -> 2x ILP, half the
// LDS reads per row. QBLK=128 per block; KV tiles of 64 keys; NS-way split.
// K  LDS: [64][128],  el = row*128 + (col ^ ((row&7)<<3))
// Vt LDS: [128][64],  el = d*64   + (key ^ SWV(d))
// P  LDS: per-wave [32][64], el = row*64 + (col ^ ((row&7)<<3))
// ---------------------------------------------------------------------------
template <int NS>
__global__ __launch_bounds__(256, 2)
void attn_fwd(const float* __restrict__ Qg, const float* __restrict__ Kg,
              const float* __restrict__ Vg, float* __restrict__ Og,
              float* __restrict__ Opart, float2* __restrict__ mlb)
{
    __shared__ __align__(16) f16 Kl[64 * 128];
    __shared__ __align__(16) f16 Vt[128 * 64];
    __shared__ __align__(16) f16 Pl[4][32 * 64];

    const int tid  = threadIdx.x;
    const int lane = tid & 63;
    const int w    = tid >> 6;
    const int c_   = lane & 15;   // A-frag m / D-frag n index
    const int g    = lane >> 4;

    // block decode: batch -> XCD; qb descending (LPT); split segment
    const int L   = blockIdx.x;
    const int bb  = L & 7;
    const int rem = L >> 3;
    const int qb  = 15 - (rem / NS);
    const int s   = rem % NS;
    const int T   = 2 * qb + 2;
    const int t0  = (T * s) / NS;
    const int t1  = (T * (s + 1)) / NS;

    const int qbase = qb * 128 + w * 16;   // + rt*64 per row-tile

    // Q fragments, pre-scaled by 1/sqrt(D) * log2(e)
    const float qs = 0.08838834764831845f * 1.4426950408889634f;
    f16x8 qf[2][4];
#pragma unroll
    for (int rt = 0; rt < 2; ++rt) {
        const float* qp = Qg + (size_t)(bb * SS + qbase + rt * 64 + c_) * DD;
#pragma unroll
        for (int kk = 0; kk < 4; ++kk) {
            const int d0 = kk * 32 + g * 8;
            f32x4 a = *(const f32x4*)(qp + d0);
            f32x4 b = *(const f32x4*)(qp + d0 + 4);
            f16x8 q;
#pragma unroll
            for (int i = 0; i < 4; ++i) {
                q[i]     = (f16)(a[i] * qs);
                q[i + 4] = (f16)(b[i] * qs);
            }
            qf[rt][kk] = q;
        }
    }

    f32x4 Oa[2][8];
#pragma unroll
    for (int rt = 0; rt < 2; ++rt)
#pragma unroll
        for (int i = 0; i < 8; ++i) Oa[rt][i] = (f32x4){0.f, 0.f, 0.f, 0.f};
    float mrun[2][4], lpart[2][4];
#pragma unroll
    for (int rt = 0; rt < 2; ++rt)
#pragma unroll
        for (int r = 0; r < 4; ++r) { mrun[rt][r] = -1e30f; lpart[rt][r] = 0.f; }

    f16* Pw = &Pl[w][0];

    // staging thread mappings
    const int krow = tid >> 5;      // K: row = krow + 8j
    const int kc4  = tid & 31;      // K: col quad
    const int vkg  = tid >> 5;      // V: key group (8 keys)
    const int vq   = tid & 31;      // V: d quad (d = vq*4 + dd)

    f32x4 kreg[8], vreg[8];

    if (t0 < t1) {
        {   // prefetch first tile
            const size_t gb = (size_t)(bb * SS + t0 * 64) * DD;
#pragma unroll
            for (int j = 0; j < 8; ++j)
                kreg[j] = *(const f32x4*)(Kg + gb + (krow + 8 * j) * DD + kc4 * 4);
#pragma unroll
            for (int i = 0; i < 8; ++i)
                vreg[i] = *(const f32x4*)(Vg + gb + (vkg * 8 + i) * DD + vq * 4);
        }

        for (int t = t0; t < t1; ++t) {
            __syncthreads();
            // ---- stage K (swizzled row-major) ----
#pragma unroll
            for (int j = 0; j < 8; ++j) {
                const int row = krow + 8 * j;
                const int el  = row * 128 + ((kc4 * 4) ^ ((row & 7) << 3));
                *(uint2*)&Kl[el] = pack4(kreg[j]);
            }
            // ---- stage V transposed ----
#pragma unroll
            for (int dd = 0; dd < 4; ++dd) {
                const int d  = vq * 4 + dd;
                const int sw = SWV(d);
#pragma unroll
                for (int h = 0; h < 2; ++h) {
                    f32x4 vv = {vreg[4 * h + 0][dd], vreg[4 * h + 1][dd],
                                vreg[4 * h + 2][dd], vreg[4 * h + 3][dd]};
                    const int el = d * 64 + ((vkg * 8 + 4 * h) ^ sw);
                    *(uint2*)&Vt[el] = pack4(vv);
                }
            }
            __syncthreads();

            // ---- issue next tile's global loads (hide under compute) ----
            if (t + 1 < t1) {
                const size_t gb = (size_t)(bb * SS + (t + 1) * 64) * DD;
#pragma unroll
                for (int j = 0; j < 8; ++j)
                    kreg[j] = *(const f32x4*)(Kg + gb + (krow + 8 * j) * DD + kc4 * 4);
#pragma unroll
                for (int i = 0; i < 8; ++i)
                    vreg[i] = *(const f32x4*)(Vg + gb + (vkg * 8 + i) * DD + vq * 4);
            }

            // ---- QK^T: shared kb, 2 row-tiles ----
            f32x4 s4[2][4];
            __builtin_amdgcn_s_setprio(1);
#pragma unroll
            for (int nb = 0; nb < 4; ++nb) {
                const int row = c_ + nb * 16;
                const int sw  = (row & 7) << 3;
                f16x8 kb[4];
#pragma unroll
                for (int kk = 0; kk < 4; ++kk)
                    kb[kk] = *(const f16x8*)&Kl[row * 128 + ((kk * 32 + g * 8) ^ sw)];
#pragma unroll
                for (int rt = 0; rt < 2; ++rt) {
                    f32x4 acc = (f32x4){0.f, 0.f, 0.f, 0.f};
#pragma unroll
                    for (int kk = 0; kk < 4; ++kk)
                        acc = __builtin_amdgcn_mfma_f32_16x16x32_f16(qf[rt][kk], kb[kk], acc, 0, 0, 0);
                    s4[rt][nb] = acc;
                }
            }
            __builtin_amdgcn_s_setprio(0);

            // ---- causal mask (t >= 2qb+rt: diagonal or fully-masked) ----
            const int kbase = t * 64;
#pragma unroll
            for (int rt = 0; rt < 2; ++rt) {
                if (t >= 2 * qb + rt) {
#pragma unroll
                    for (int nb = 0; nb < 4; ++nb)
#pragma unroll
                        for (int r = 0; r < 4; ++r) {
                            const int kj = kbase + nb * 16 + c_;
                            const int qi = qbase + rt * 64 + g * 4 + r;
                            if (kj > qi) s4[rt][nb][r] = -1e30f;
                        }
                }
            }

            // ---- softmax: wave-max fast path, per-row slow path ----
            float wm = -1e30f;
#pragma unroll
            for (int rt = 0; rt < 2; ++rt)
#pragma unroll
                for (int nb = 0; nb < 4; ++nb) {
                    f32x4 v = s4[rt][nb];
                    wm = fmaxf(wm, fmaxf(fmaxf(v[0], v[1]), fmaxf(v[2], v[3])));
                }
            wm = fmaxf(wm, __shfl_xor(wm, 1));
            wm = fmaxf(wm, __shfl_xor(wm, 2));
            wm = fmaxf(wm, __shfl_xor(wm, 4));
            wm = fmaxf(wm, __shfl_xor(wm, 8));
            wm = fmaxf(wm, __shfl_xor(wm, 16));
            wm = fmaxf(wm, __shfl_xor(wm, 32));
            float mrmin = 1e30f;
#pragma unroll
            for (int rt = 0; rt < 2; ++rt)
#pragma unroll
                for (int r = 0; r < 4; ++r) mrmin = fminf(mrmin, mrun[rt][r]);

            if (!__all(wm - mrmin <= 8.0f)) {
                // slow path: exact per-row reduce + defer-max
                float sc[2][4];
                float scmin = 1.0f;
#pragma unroll
                for (int rt = 0; rt < 2; ++rt)
#pragma unroll
                    for (int r = 0; r < 4; ++r) {
                        float pm = fmaxf(fmaxf(s4[rt][0][r], s4[rt][1][r]),
                                         fmaxf(s4[rt][2][r], s4[rt][3][r]));
                        pm = fmaxf(pm, __shfl_xor(pm, 1));
                        pm = fmaxf(pm, __shfl_xor(pm, 2));
                        pm = fmaxf(pm, __shfl_xor(pm, 4));
                        pm = fmaxf(pm, __shfl_xor(pm, 8));
                        const bool keep = (pm - mrun[rt][r] <= 8.0f);
                        sc[rt][r] = keep ? 1.0f : fast_exp2(mrun[rt][r] - pm);
                        if (!keep) mrun[rt][r] = pm;
                        scmin = fminf(scmin, sc[rt][r]);
                    }
                if (scmin < 1.0f) {
#pragma unroll
                    for (int rt = 0; rt < 2; ++rt)
#pragma unroll
                        for (int r = 0; r < 4; ++r) {
                            lpart[rt][r] *= sc[rt][r];
#pragma unroll
                            for (int dblk = 0; dblk < 8; ++dblk)
                                Oa[rt][dblk][r] *= sc[rt][r];
                        }
                }
            }

            // ---- P = exp2(S - m), pack, write to LDS ----
#pragma unroll
            for (int rt = 0; rt < 2; ++rt)
#pragma unroll
                for (int nb = 0; nb < 4; ++nb) {
                    float pv[4];
#pragma unroll
                    for (int r = 0; r < 4; ++r) {
                        pv[r] = fast_exp2(s4[rt][nb][r] - mrun[rt][r]);
                        lpart[rt][r] += pv[r];
                    }
                    f16x2 p01 = cvt_pk(pv[0], pv[1]);
                    f16x2 p23 = cvt_pk(pv[2], pv[3]);
#pragma unroll
                    for (int r = 0; r < 4; ++r) {
                        const int row = rt * 16 + g * 4 + r;
                        const f16 hv = (r < 2) ? p01[r & 1] : p23[r & 1];
                        Pw[row * 64 + ((nb * 16 + c_) ^ ((row & 7) << 3))] = hv;
                    }
                }

            // ---- PV: shared vb, 2 row-tiles ----
#pragma unroll
            for (int ks = 0; ks < 2; ++ks) {
                f16x8 pa[2];
#pragma unroll
                for (int rt = 0; rt < 2; ++rt) {
                    const int rr = rt * 16 + c_;
                    pa[rt] = *(const f16x8*)&Pw[rr * 64 + ((ks * 32 + g * 8) ^ ((c_ & 7) << 3))];
                }
                __builtin_amdgcn_s_setprio(1);
#pragma unroll
                for (int dblk = 0; dblk < 8; ++dblk) {
                    const int d  = dblk * 16 + c_;
                    f16x8 vb = *(const f16x8*)&Vt[d * 64 + ((ks * 32 + g * 8) ^ SWV(d))];
#pragma unroll
                    for (int rt = 0; rt < 2; ++rt)
                        Oa[rt][dblk] = __builtin_amdgcn_mfma_f32_16x16x32_f16(pa[rt], vb, Oa[rt][dblk], 0, 0, 0);
                }
                __builtin_amdgcn_s_setprio(0);
            }
        }
    }

    // ---- reduce deferred l across the 16 key-lanes ----
    float lrun[2][4];
#pragma unroll
    for (int rt = 0; rt < 2; ++rt)
#pragma unroll
        for (int r = 0; r < 4; ++r) {
            float v = lpart[rt][r];
            v += __shfl_xor(v, 1);
            v += __shfl_xor(v, 2);
            v += __shfl_xor(v, 4);
            v += __shfl_xor(v, 8);
            lrun[rt][r] = v;
        }

    // ---- epilogue ----
    if (NS == 1) {
#pragma unroll
        for (int rt = 0; rt < 2; ++rt)
#pragma unroll
            for (int r = 0; r < 4; ++r) {
                const int qrow = qbase + rt * 64 + g * 4 + r;
                float* dst = Og + (size_t)(bb * SS + qrow) * DD + c_;
                const float inv = 1.0f / lrun[rt][r];
#pragma unroll
                for (int dblk = 0; dblk < 8; ++dblk)
                    dst[dblk * 16] = Oa[rt][dblk][r] * inv;
            }
    } else {
        float*  od  = (s == 0) ? Og : (Opart + (size_t)(s - 1) * BB * SS * DD);
        float2* mld = mlb + (size_t)s * BB * SS;
#pragma unroll
        for (int rt = 0; rt < 2; ++rt)
#pragma unroll
            for (int r = 0; r < 4; ++r) {
                const int qrow = qbase + rt * 64 + g * 4 + r;
                float* dst = od + (size_t)(bb * SS + qrow) * DD + c_;
#pragma unroll
                for (int dblk = 0; dblk < 8; ++dblk)
                    dst[dblk * 16] = Oa[rt][dblk][r];
                if (c_ == 0) mld[bb * SS + qrow] = make_float2(mrun[rt][r], lrun[rt][r]);
            }
    }
}

// ---------------------------------------------------------------------------
// Merge NS KV-split partials: out = (sum Oi*ei) / (sum li*ei)
// ---------------------------------------------------------------------------
template <int NS>
__global__ __launch_bounds__(256)
void merge_kernel(float* __restrict__ out, const float* __restrict__ Opart,
                  const float2* __restrict__ mlb)
{
    const int idx = blockIdx.x * 256 + threadIdx.x;  // float4 units
    const int row = idx >> 5;
    float2 ml[NS];
#pragma unroll
    for (int i = 0; i < NS; ++i) ml[i] = mlb[(size_t)i * BB * SS + row];
    float mm = ml[0].x;
#pragma unroll
    for (int i = 1; i < NS; ++i) mm = fmaxf(mm, ml[i].x);
    float e[NS], den = 0.f;
#pragma unroll
    for (int i = 0; i < NS; ++i) {
        e[i] = fast_exp2(ml[i].x - mm);
        den += ml[i].y * e[i];
    }
    const float inv = 1.0f / den;
    float4 o = ((const float4*)out)[idx];
    float4 acc;
    acc.x = o.x * e[0]; acc.y = o.y * e[0];
    acc.z = o.z * e[0]; acc.w = o.w * e[0];
#pragma unroll
    for (int i = 1; i < NS; ++i) {
        float4 p = ((const float4*)(Opart + (size_t)(i - 1) * BB * SS * DD))[idx];
        acc.x += p.x * e[i]; acc.y += p.y * e[i];
        acc.z += p.z * e[i]; acc.w += p.w * e[i];
    }
    acc.x *= inv; acc.y *= inv; acc.z *= inv; acc.w *= inv;
    ((float4*)out)[idx] = acc;
}

extern "C" void kernel_launch(void* const* d_in, const int* in_sizes, int n_in,
                              void* d_out, int out_size, void* d_ws, size_t ws_size,
                              hipStream_t stream)
{
    const float* Q = (const float*)d_in[0];
    const float* K = (const float*)d_in[1];
    const float* V = (const float*)d_in[2];
    float* out = (float*)d_out;

    const size_t OB  = (size_t)BB * SS * DD * sizeof(float);  // 8 MB
    const size_t MB_ = (size_t)BB * SS * sizeof(float2);      // 128 KB
    const int mergeGrid = BB * SS * DD / 4 / 256;             // 2048

    const size_t need4 = 3 * OB + 4 * MB_;
    const size_t need2 = 1 * OB + 2 * MB_;

    if (ws_size >= need4) {
        float*  Op  = (float*)d_ws;
        float2* mlb = (float2*)((char*)d_ws + 3 * OB);
        hipLaunchKernelGGL((attn_fwd<4>), dim3(8 * 16 * 4), dim3(256), 0, stream,
                           Q, K, V, out, Op, mlb);
        hipLaunchKernelGGL((merge_kernel<4>), dim3(mergeGrid), dim3(256), 0, stream,
                           out, Op, mlb);
    } else if (ws_size >= need2) {
        float*  Op  = (float*)d_ws;
        float2* mlb = (float2*)((char*)d_ws + 1 * OB);
        hipLaunchKernelGGL((attn_fwd<2>), dim3(8 * 16 * 2), dim3(256), 0, stream,
                           Q, K, V, out, Op, mlb);
        hipLaunchKernelGGL((merge_kernel<2>), dim3(mergeGrid), dim3(256), 0, stream,
                           out, Op, mlb);
    } else {
        hipLaunchKernelGGL((attn_fwd<1>), dim3(8 * 16), dim3(256), 0, stream,
                           Q, K, V, out, (float*)nullptr, (float2*)nullptr);
    }
}

// Round 6
// 113.823 us; speedup vs baseline: 1.3871x; 1.3871x over previous
//
#include <hip/hip_runtime.h>

#define BB 8
#define SS 2048
#define DD 128
#define SEG ((size_t)BB * SS * DD)   // elements per partial segment

typedef _Float16 f16;
typedef _Float16 f16x2 __attribute__((ext_vector_type(2)));
typedef __fp16 h16x2 __attribute__((ext_vector_type(2)));
typedef _Float16 f16x8 __attribute__((ext_vector_type(8)));
typedef float f32x4 __attribute__((ext_vector_type(4)));

// Vt LDS swizzle: spreads banks for BOTH staging writes (d = vq*4+dd) and
// PV reads (d = dblk*16+c_).
#define SWV(d) ((((d) & 7) ^ (((d) >> 3) & 7)) << 3)

#define DEFER_THR 4.0f   // exp2-domain defer-max threshold: P <= 16, f16-safe

static __device__ __forceinline__ float fast_exp2(float x) {
#if __has_builtin(__builtin_amdgcn_exp2f)
    return __builtin_amdgcn_exp2f(x);
#else
    return exp2f(x);
#endif
}

static __device__ __forceinline__ f16x2 cvt_pk(float a, float b) {
    h16x2 r = __builtin_amdgcn_cvt_pkrtz(a, b);
    return __builtin_bit_cast(f16x2, r);
}

// pack 4 f32 -> 4 f16 (RTZ) as uint2 for one b64 LDS write
static __device__ __forceinline__ uint2 pack4(f32x4 v) {
    f16x2 lo = cvt_pk(v[0], v[1]);
    f16x2 hi = cvt_pk(v[2], v[3]);
    uint2 u;
    u.x = __builtin_bit_cast(unsigned int, lo);
    u.y = __builtin_bit_cast(unsigned int, hi);
    return u;
}

// ---------------------------------------------------------------------------
// Flash attention forward, causal. f16 MFMA 16x16x32, fp32 softmax/accum.
// 256 threads = 4 waves; each wave owns 16 q rows (QBLK=64 per block).
// NS-way KV split (grid = 8*32*NS); partials stored f16; merge combines.
// K  LDS: [64][128],  el = row*128 + (col ^ ((row&7)<<3))
// Vt LDS: [128][64],  el = d*64   + (key ^ SWV(d))
// P  LDS: per-wave [16][64], el = row*64 + (col ^ ((row&7)<<3))
// ---------------------------------------------------------------------------
template <int NS>
__global__ __launch_bounds__(256, 2)
void attn_fwd(const float* __restrict__ Qg, const float* __restrict__ Kg,
              const float* __restrict__ Vg, float* __restrict__ Og,
              f16* __restrict__ Opf, float2* __restrict__ mlb)
{
    __shared__ __align__(16) f16 Kl[64 * 128];
    __shared__ __align__(16) f16 Vt[128 * 64];
    __shared__ __align__(16) f16 Pl[4][16 * 64];

    const int tid  = threadIdx.x;
    const int lane = tid & 63;
    const int w    = tid >> 6;
    const int c_   = lane & 15;   // key col (QK^T) / d col (PV out)
    const int g    = lane >> 4;

    // block decode: batch -> XCD; qb descending (LPT); split segment
    const int L   = blockIdx.x;
    const int bb  = L & 7;
    const int rem = L >> 3;
    const int qb  = 31 - (rem / NS);
    const int sg  = rem % NS;
    const int T   = qb + 1;
    const int t0  = (T * sg) / NS;
    const int t1  = (T * (sg + 1)) / NS;

    const int qrow0 = qb * 64 + w * 16;

    // Q fragments, pre-scaled by 1/sqrt(D) * log2(e)
    const float qs = 0.08838834764831845f * 1.4426950408889634f;
    f16x8 qf[4];
    {
        const float* qp = Qg + (size_t)(bb * SS + qrow0 + c_) * DD;
#pragma unroll
        for (int kk = 0; kk < 4; ++kk) {
            const int d0 = kk * 32 + g * 8;
            f32x4 a = *(const f32x4*)(qp + d0);
            f32x4 b = *(const f32x4*)(qp + d0 + 4);
            f16x8 q;
#pragma unroll
            for (int i = 0; i < 4; ++i) {
                q[i]     = (f16)(a[i] * qs);
                q[i + 4] = (f16)(b[i] * qs);
            }
            qf[kk] = q;
        }
    }

    f32x4 Oa[8];
#pragma unroll
    for (int i = 0; i < 8; ++i) Oa[i] = (f32x4){0.f, 0.f, 0.f, 0.f};
    float mrun[4] = {-1e30f, -1e30f, -1e30f, -1e30f};
    float lpart[4] = {0.f, 0.f, 0.f, 0.f};   // per-lane partial l

    f16* Pw = &Pl[w][0];

    // staging thread mappings
    const int krow = tid >> 5;      // K: row = krow + 8j
    const int kc4  = tid & 31;      // K: col quad
    const int vkg  = tid >> 5;      // V: key group (8 keys)
    const int vq   = tid & 31;      // V: d quad (d = vq*4 + dd)

    f32x4 kreg[8], vreg[8];

    if (t0 < t1) {
        {   // prefetch first tile
            const size_t gb = (size_t)(bb * SS + t0 * 64) * DD;
#pragma unroll
            for (int j = 0; j < 8; ++j)
                kreg[j] = *(const f32x4*)(Kg + gb + (krow + 8 * j) * DD + kc4 * 4);
#pragma unroll
            for (int i = 0; i < 8; ++i)
                vreg[i] = *(const f32x4*)(Vg + gb + (vkg * 8 + i) * DD + vq * 4);
        }

        for (int t = t0; t < t1; ++t) {
            __syncthreads();
            // ---- stage K (swizzled row-major) ----
#pragma unroll
            for (int j = 0; j < 8; ++j) {
                const int row = krow + 8 * j;
                const int el  = row * 128 + ((kc4 * 4) ^ ((row & 7) << 3));
                *(uint2*)&Kl[el] = pack4(kreg[j]);
            }
            // ---- stage V transposed (bank-spread swizzle) ----
#pragma unroll
            for (int dd = 0; dd < 4; ++dd) {
                const int d  = vq * 4 + dd;
                const int sw = SWV(d);
#pragma unroll
                for (int h = 0; h < 2; ++h) {
                    f32x4 vv = {vreg[4 * h + 0][dd], vreg[4 * h + 1][dd],
                                vreg[4 * h + 2][dd], vreg[4 * h + 3][dd]};
                    const int el = d * 64 + ((vkg * 8 + 4 * h) ^ sw);
                    *(uint2*)&Vt[el] = pack4(vv);
                }
            }
            __syncthreads();

            // ---- issue next tile's global loads (hide under compute) ----
            if (t + 1 < t1) {
                const size_t gb = (size_t)(bb * SS + (t + 1) * 64) * DD;
#pragma unroll
                for (int j = 0; j < 8; ++j)
                    kreg[j] = *(const f32x4*)(Kg + gb + (krow + 8 * j) * DD + kc4 * 4);
#pragma unroll
                for (int i = 0; i < 8; ++i)
                    vreg[i] = *(const f32x4*)(Vg + gb + (vkg * 8 + i) * DD + vq * 4);
            }

            const int kbase = t * 64;

            // ---- QK^T ----
            f32x4 s4[4];
            __builtin_amdgcn_s_setprio(1);
#pragma unroll
            for (int nb = 0; nb < 4; ++nb) {
                f32x4 acc = (f32x4){0.f, 0.f, 0.f, 0.f};
                const int row = c_ + nb * 16;
                const int sw  = (row & 7) << 3;
#pragma unroll
                for (int kk = 0; kk < 4; ++kk) {
                    f16x8 kb = *(const f16x8*)&Kl[row * 128 + ((kk * 32 + g * 8) ^ sw)];
                    acc = __builtin_amdgcn_mfma_f32_16x16x32_f16(qf[kk], kb, acc, 0, 0, 0);
                }
                s4[nb] = acc;
            }
            __builtin_amdgcn_s_setprio(0);

            // ---- causal mask (diagonal tile only) ----
            if (t == qb) {
#pragma unroll
                for (int nb = 0; nb < 4; ++nb)
#pragma unroll
                    for (int r = 0; r < 4; ++r) {
                        const int kj = kbase + nb * 16 + c_;
                        const int qi = qrow0 + g * 4 + r;
                        if (kj > qi) s4[nb][r] = -1e30f;
                    }
            }

            // ---- softmax: wave-max fast path, per-row slow path ----
            float wm = -1e30f;
#pragma unroll
            for (int nb = 0; nb < 4; ++nb) {
                f32x4 v = s4[nb];
                wm = fmaxf(wm, fmaxf(fmaxf(v[0], v[1]), fmaxf(v[2], v[3])));
            }
            wm = fmaxf(wm, __shfl_xor(wm, 1));
            wm = fmaxf(wm, __shfl_xor(wm, 2));
            wm = fmaxf(wm, __shfl_xor(wm, 4));
            wm = fmaxf(wm, __shfl_xor(wm, 8));
            wm = fmaxf(wm, __shfl_xor(wm, 16));
            wm = fmaxf(wm, __shfl_xor(wm, 32));
            float mrmin = fminf(fminf(mrun[0], mrun[1]), fminf(mrun[2], mrun[3]));

            if (!__all(wm - mrmin <= DEFER_THR)) {
                // slow path: exact per-row reduce + defer-max
                float sc[4];
                float scmin = 1.0f;
#pragma unroll
                for (int r = 0; r < 4; ++r) {
                    float pm = fmaxf(fmaxf(s4[0][r], s4[1][r]),
                                     fmaxf(s4[2][r], s4[3][r]));
                    pm = fmaxf(pm, __shfl_xor(pm, 1));
                    pm = fmaxf(pm, __shfl_xor(pm, 2));
                    pm = fmaxf(pm, __shfl_xor(pm, 4));
                    pm = fmaxf(pm, __shfl_xor(pm, 8));
                    const bool keep = (pm - mrun[r] <= DEFER_THR);
                    sc[r] = keep ? 1.0f : fast_exp2(mrun[r] - pm);
                    if (!keep) mrun[r] = pm;
                    scmin = fminf(scmin, sc[r]);
                }
                if (scmin < 1.0f) {
#pragma unroll
                    for (int r = 0; r < 4; ++r) {
                        lpart[r] *= sc[r];
#pragma unroll
                        for (int dblk = 0; dblk < 8; ++dblk)
                            Oa[dblk][r] *= sc[r];
                    }
                }
            }

            // ---- P = exp2(S - m), pack, write to LDS ----
#pragma unroll
            for (int nb = 0; nb < 4; ++nb) {
                float pv[4];
#pragma unroll
                for (int r = 0; r < 4; ++r) {
                    pv[r] = fast_exp2(s4[nb][r] - mrun[r]);
                    lpart[r] += pv[r];
                }
                f16x2 p01 = cvt_pk(pv[0], pv[1]);
                f16x2 p23 = cvt_pk(pv[2], pv[3]);
#pragma unroll
                for (int r = 0; r < 4; ++r) {
                    const int row = g * 4 + r;
                    const f16 hv = (r < 2) ? p01[r & 1] : p23[r & 1];
                    Pw[row * 64 + ((nb * 16 + c_) ^ ((row & 7) << 3))] = hv;
                }
            }

            // ---- PV: A = P, B = Vt ----
#pragma unroll
            for (int ks = 0; ks < 2; ++ks) {
                f16x8 pa = *(const f16x8*)&Pw[c_ * 64 + ((ks * 32 + g * 8) ^ ((c_ & 7) << 3))];
                __builtin_amdgcn_s_setprio(1);
#pragma unroll
                for (int dblk = 0; dblk < 8; ++dblk) {
                    const int d  = dblk * 16 + c_;
                    f16x8 vb = *(const f16x8*)&Vt[d * 64 + ((ks * 32 + g * 8) ^ SWV(d))];
                    Oa[dblk] = __builtin_amdgcn_mfma_f32_16x16x32_f16(pa, vb, Oa[dblk], 0, 0, 0);
                }
                __builtin_amdgcn_s_setprio(0);
            }
        }
    }

    // ---- reduce deferred l across the 16 key-lanes ----
    float lrun[4];
#pragma unroll
    for (int r = 0; r < 4; ++r) {
        float v = lpart[r];
        v += __shfl_xor(v, 1);
        v += __shfl_xor(v, 2);
        v += __shfl_xor(v, 4);
        v += __shfl_xor(v, 8);
        lrun[r] = v;
    }

    // ---- epilogue ----
    if (NS == 1) {
#pragma unroll
        for (int r = 0; r < 4; ++r) {
            const int qrow = qrow0 + g * 4 + r;
            float* dst = Og + (size_t)(bb * SS + qrow) * DD + c_;
            const float inv = 1.0f / lrun[r];
#pragma unroll
            for (int dblk = 0; dblk < 8; ++dblk)
                dst[dblk * 16] = Oa[dblk][r] * inv;
        }
    } else {
        // unnormalized f16 partial + (m, l)
        f16*    od  = Opf + (size_t)sg * SEG;
        float2* mld = mlb + (size_t)sg * BB * SS;
#pragma unroll
        for (int r = 0; r < 4; ++r) {
            const int qrow = qrow0 + g * 4 + r;
            f16* dst = od + (size_t)(bb * SS + qrow) * DD + c_;
#pragma unroll
            for (int dblk = 0; dblk < 8; ++dblk)
                dst[dblk * 16] = (f16)Oa[dblk][r];
            if (c_ == 0) mld[bb * SS + qrow] = make_float2(mrun[r], lrun[r]);
        }
    }
}

// ---------------------------------------------------------------------------
// Merge NS KV-split f16 partials: out = (sum Oi*ei) / (sum li*ei)
// Each thread handles 8 contiguous d-elements of one row.
// ---------------------------------------------------------------------------
template <int NS>
__global__ __launch_bounds__(256)
void merge_kernel(float* __restrict__ out, const f16* __restrict__ Opf,
                  const float2* __restrict__ mlb)
{
    const int idx = blockIdx.x * 256 + threadIdx.x;  // 8-elem units
    const int row = idx >> 4;                        // 16 units per row
    float2 ml[NS];
#pragma unroll
    for (int i = 0; i < NS; ++i) ml[i] = mlb[(size_t)i * BB * SS + row];
    float mm = ml[0].x;
#pragma unroll
    for (int i = 1; i < NS; ++i) mm = fmaxf(mm, ml[i].x);
    float e[NS], den = 0.f;
#pragma unroll
    for (int i = 0; i < NS; ++i) {
        e[i] = fast_exp2(ml[i].x - mm);
        den += ml[i].y * e[i];
    }
    const float inv = 1.0f / den;

    float acc[8] = {0.f, 0.f, 0.f, 0.f, 0.f, 0.f, 0.f, 0.f};
#pragma unroll
    for (int i = 0; i < NS; ++i) {
        f16x8 v = *(const f16x8*)(Opf + (size_t)i * SEG + (size_t)idx * 8);
#pragma unroll
        for (int j = 0; j < 8; ++j) acc[j] += (float)v[j] * e[i];
    }
    float4 o0, o1;
    o0.x = acc[0] * inv; o0.y = acc[1] * inv; o0.z = acc[2] * inv; o0.w = acc[3] * inv;
    o1.x = acc[4] * inv; o1.y = acc[5] * inv; o1.z = acc[6] * inv; o1.w = acc[7] * inv;
    float4* dst = (float4*)(out + (size_t)idx * 8);
    dst[0] = o0;
    dst[1] = o1;
}

extern "C" void kernel_launch(void* const* d_in, const int* in_sizes, int n_in,
                              void* d_out, int out_size, void* d_ws, size_t ws_size,
                              hipStream_t stream)
{
    const float* Q = (const float*)d_in[0];
    const float* K = (const float*)d_in[1];
    const float* V = (const float*)d_in[2];
    float* out = (float*)d_out;

    const size_t OPB = SEG * sizeof(f16);                 // 4 MB per segment
    const size_t MLB = (size_t)BB * SS * sizeof(float2);  // 128 KB per segment
    const int mergeGrid = (int)(SEG / 8 / 256);           // 1024

    const size_t need8 = 8 * OPB + 8 * MLB;
    const size_t need4 = 4 * OPB + 4 * MLB;

    if (ws_size >= need8) {
        f16*    Opf = (f16*)d_ws;
        float2* mlb = (float2*)((char*)d_ws + 8 * OPB);
        hipLaunchKernelGGL((attn_fwd<8>), dim3(8 * 32 * 8), dim3(256), 0, stream,
                           Q, K, V, out, Opf, mlb);
        hipLaunchKernelGGL((merge_kernel<8>), dim3(mergeGrid), dim3(256), 0, stream,
                           out, Opf, mlb);
    } else if (ws_size >= need4) {
        f16*    Opf = (f16*)d_ws;
        float2* mlb = (float2*)((char*)d_ws + 4 * OPB);
        hipLaunchKernelGGL((attn_fwd<4>), dim3(8 * 32 * 4), dim3(256), 0, stream,
                           Q, K, V, out, Opf, mlb);
        hipLaunchKernelGGL((merge_kernel<4>), dim3(mergeGrid), dim3(256), 0, stream,
                           out, Opf, mlb);
    } else {
        hipLaunchKernelGGL((attn_fwd<1>), dim3(8 * 32), dim3(256), 0, stream,
                           Q, K, V, out, (f16*)nullptr, (float2*)nullptr);
    }
}

// Round 7
// 103.648 us; speedup vs baseline: 1.5232x; 1.0982x over previous
//
#include <hip/hip_runtime.h>

#define BB 8
#define SS 2048
#define DD 128
#define SEG ((size_t)BB * SS * DD)   // elements per partial segment

typedef _Float16 f16;
typedef _Float16 f16x2 __attribute__((ext_vector_type(2)));
typedef __fp16 h16x2 __attribute__((ext_vector_type(2)));
typedef _Float16 f16x8 __attribute__((ext_vector_type(8)));
typedef float f32x4 __attribute__((ext_vector_type(4)));

// Vt LDS swizzle: spreads banks for BOTH staging writes (d = vq*4+dd) and
// PV reads (d = dblk*16+c_).
#define SWV(d) ((((d) & 7) ^ (((d) >> 3) & 7)) << 3)

#define DEFER_THR 4.0f   // exp2-domain defer-max threshold: P <= 16, f16-safe

static __device__ __forceinline__ float fast_exp2(float x) {
#if __has_builtin(__builtin_amdgcn_exp2f)
    return __builtin_amdgcn_exp2f(x);
#else
    return exp2f(x);
#endif
}

static __device__ __forceinline__ f16x2 cvt_pk(float a, float b) {
    h16x2 r = __builtin_amdgcn_cvt_pkrtz(a, b);
    return __builtin_bit_cast(f16x2, r);
}

// pack 4 f32 -> 4 f16 (RTZ) as uint2 for one b64 LDS write
static __device__ __forceinline__ uint2 pack4(f32x4 v) {
    f16x2 lo = cvt_pk(v[0], v[1]);
    f16x2 hi = cvt_pk(v[2], v[3]);
    uint2 u;
    u.x = __builtin_bit_cast(unsigned int, lo);
    u.y = __builtin_bit_cast(unsigned int, hi);
    return u;
}

// ---------------------------------------------------------------------------
// Flash attention forward, causal. f16 MFMA 16x16x32, fp32 softmax/accum.
// 256 threads = 4 waves; each wave owns 16 q rows (QBLK=64 per block).
// NS-way KV split (grid = 8*32*NS); partials stored f16; merge combines.
// DOUBLE-BUFFERED K/V LDS: one barrier per tile; tile t+1 staged into
// buf[t&1^1] while tile t is computed from buf[t&1]; global loads issued a
// full iteration ahead so the vmcnt wait at stage time is instant.
// K  LDS: [2][64][128], el = row*128 + (col ^ ((row&7)<<3))
// Vt LDS: [2][128][64], el = d*64   + (key ^ SWV(d))
// P  LDS: per-wave [16][64], el = row*64 + (col ^ ((row&7)<<3))
// ---------------------------------------------------------------------------
template <int NS>
__global__ __launch_bounds__(256, 2)
void attn_fwd(const float* __restrict__ Qg, const float* __restrict__ Kg,
              const float* __restrict__ Vg, float* __restrict__ Og,
              f16* __restrict__ Opf, float2* __restrict__ mlb)
{
    __shared__ __align__(16) f16 Kl[2][64 * 128];
    __shared__ __align__(16) f16 Vt[2][128 * 64];
    __shared__ __align__(16) f16 Pl[4][16 * 64];

    const int tid  = threadIdx.x;
    const int lane = tid & 63;
    const int w    = tid >> 6;
    const int c_   = lane & 15;   // key col (QK^T) / d col (PV out)
    const int g    = lane >> 4;

    // block decode: batch -> XCD; qb descending (LPT); split segment
    const int L   = blockIdx.x;
    const int bb  = L & 7;
    const int rem = L >> 3;
    const int qb  = 31 - (rem / NS);
    const int sg  = rem % NS;
    const int T   = qb + 1;
    const int t0  = (T * sg) / NS;
    const int t1  = (T * (sg + 1)) / NS;

    const int qrow0 = qb * 64 + w * 16;

    // Q fragments, pre-scaled by 1/sqrt(D) * log2(e)
    const float qs = 0.08838834764831845f * 1.4426950408889634f;
    f16x8 qf[4];
    {
        const float* qp = Qg + (size_t)(bb * SS + qrow0 + c_) * DD;
#pragma unroll
        for (int kk = 0; kk < 4; ++kk) {
            const int d0 = kk * 32 + g * 8;
            f32x4 a = *(const f32x4*)(qp + d0);
            f32x4 b = *(const f32x4*)(qp + d0 + 4);
            f16x8 q;
#pragma unroll
            for (int i = 0; i < 4; ++i) {
                q[i]     = (f16)(a[i] * qs);
                q[i + 4] = (f16)(b[i] * qs);
            }
            qf[kk] = q;
        }
    }

    f32x4 Oa[8];
#pragma unroll
    for (int i = 0; i < 8; ++i) Oa[i] = (f32x4){0.f, 0.f, 0.f, 0.f};
    float mrun[4] = {-1e30f, -1e30f, -1e30f, -1e30f};
    float lpart[4] = {0.f, 0.f, 0.f, 0.f};   // per-lane partial l

    f16* Pw = &Pl[w][0];

    // staging thread mappings
    const int krow = tid >> 5;      // K: row = krow + 8j
    const int kc4  = tid & 31;      // K: col quad
    const int vkg  = tid >> 5;      // V: key group (8 keys)
    const int vq   = tid & 31;      // V: d quad (d = vq*4 + dd)

    f32x4 kreg[8], vreg[8];

#define LOADT(tt)                                                              \
    {                                                                          \
        const size_t gb = (size_t)(bb * SS + (tt) * 64) * DD;                  \
        _Pragma("unroll")                                                      \
        for (int j = 0; j < 8; ++j)                                            \
            kreg[j] = *(const f32x4*)(Kg + gb + (krow + 8 * j) * DD + kc4 * 4);\
        _Pragma("unroll")                                                      \
        for (int i = 0; i < 8; ++i)                                            \
            vreg[i] = *(const f32x4*)(Vg + gb + (vkg * 8 + i) * DD + vq * 4);  \
    }

#define STAGE_K(pb_)                                                           \
    {                                                                          \
        _Pragma("unroll")                                                      \
        for (int j = 0; j < 8; ++j) {                                          \
            const int row = krow + 8 * j;                                      \
            const int el  = row * 128 + ((kc4 * 4) ^ ((row & 7) << 3));        \
            *(uint2*)&Kl[pb_][el] = pack4(kreg[j]);                            \
        }                                                                      \
    }

#define STAGE_V(pb_)                                                           \
    {                                                                          \
        _Pragma("unroll")                                                      \
        for (int dd = 0; dd < 4; ++dd) {                                       \
            const int d  = vq * 4 + dd;                                        \
            const int sw = SWV(d);                                             \
            _Pragma("unroll")                                                  \
            for (int h = 0; h < 2; ++h) {                                      \
                f32x4 vv = {vreg[4 * h + 0][dd], vreg[4 * h + 1][dd],          \
                            vreg[4 * h + 2][dd], vreg[4 * h + 3][dd]};         \
                const int el = d * 64 + ((vkg * 8 + 4 * h) ^ sw);              \
                *(uint2*)&Vt[pb_][el] = pack4(vv);                             \
            }                                                                  \
        }                                                                      \
    }

    if (t0 < t1) {
        // prologue: fill buf[t0&1] with tile t0; issue loads for t0+1
        LOADT(t0);
        STAGE_K(t0 & 1);
        STAGE_V(t0 & 1);
        if (t0 + 1 < t1) LOADT(t0 + 1);
        __syncthreads();

        for (int t = t0; t < t1; ++t) {
            const int pb = t & 1;
            const bool more = (t + 1 < t1);
            const int kbase = t * 64;

            // ---- QK^T from Kl[pb] ----
            f32x4 s4[4];
            __builtin_amdgcn_s_setprio(1);
#pragma unroll
            for (int nb = 0; nb < 4; ++nb) {
                f32x4 acc = (f32x4){0.f, 0.f, 0.f, 0.f};
                const int row = c_ + nb * 16;
                const int sw  = (row & 7) << 3;
#pragma unroll
                for (int kk = 0; kk < 4; ++kk) {
                    f16x8 kb = *(const f16x8*)&Kl[pb][row * 128 + ((kk * 32 + g * 8) ^ sw)];
                    acc = __builtin_amdgcn_mfma_f32_16x16x32_f16(qf[kk], kb, acc, 0, 0, 0);
                }
                s4[nb] = acc;
            }
            __builtin_amdgcn_s_setprio(0);

            // ---- stage K(t+1) into other buffer (hides under softmax) ----
            if (more) STAGE_K(pb ^ 1);

            // ---- causal mask (diagonal tile only) ----
            if (t == qb) {
#pragma unroll
                for (int nb = 0; nb < 4; ++nb)
#pragma unroll
                    for (int r = 0; r < 4; ++r) {
                        const int kj = kbase + nb * 16 + c_;
                        const int qi = qrow0 + g * 4 + r;
                        if (kj > qi) s4[nb][r] = -1e30f;
                    }
            }

            // ---- softmax: wave-max fast path, per-row slow path ----
            float wm = -1e30f;
#pragma unroll
            for (int nb = 0; nb < 4; ++nb) {
                f32x4 v = s4[nb];
                wm = fmaxf(wm, fmaxf(fmaxf(v[0], v[1]), fmaxf(v[2], v[3])));
            }
            wm = fmaxf(wm, __shfl_xor(wm, 1));
            wm = fmaxf(wm, __shfl_xor(wm, 2));
            wm = fmaxf(wm, __shfl_xor(wm, 4));
            wm = fmaxf(wm, __shfl_xor(wm, 8));
            wm = fmaxf(wm, __shfl_xor(wm, 16));
            wm = fmaxf(wm, __shfl_xor(wm, 32));
            float mrmin = fminf(fminf(mrun[0], mrun[1]), fminf(mrun[2], mrun[3]));

            if (!__all(wm - mrmin <= DEFER_THR)) {
                float sc[4];
                float scmin = 1.0f;
#pragma unroll
                for (int r = 0; r < 4; ++r) {
                    float pm = fmaxf(fmaxf(s4[0][r], s4[1][r]),
                                     fmaxf(s4[2][r], s4[3][r]));
                    pm = fmaxf(pm, __shfl_xor(pm, 1));
                    pm = fmaxf(pm, __shfl_xor(pm, 2));
                    pm = fmaxf(pm, __shfl_xor(pm, 4));
                    pm = fmaxf(pm, __shfl_xor(pm, 8));
                    const bool keep = (pm - mrun[r] <= DEFER_THR);
                    sc[r] = keep ? 1.0f : fast_exp2(mrun[r] - pm);
                    if (!keep) mrun[r] = pm;
                    scmin = fminf(scmin, sc[r]);
                }
                if (scmin < 1.0f) {
#pragma unroll
                    for (int r = 0; r < 4; ++r) {
                        lpart[r] *= sc[r];
#pragma unroll
                        for (int dblk = 0; dblk < 8; ++dblk)
                            Oa[dblk][r] *= sc[r];
                    }
                }
            }

            // ---- P = exp2(S - m), pack, write to LDS ----
#pragma unroll
            for (int nb = 0; nb < 4; ++nb) {
                float pv[4];
#pragma unroll
                for (int r = 0; r < 4; ++r) {
                    pv[r] = fast_exp2(s4[nb][r] - mrun[r]);
                    lpart[r] += pv[r];
                }
                f16x2 p01 = cvt_pk(pv[0], pv[1]);
                f16x2 p23 = cvt_pk(pv[2], pv[3]);
#pragma unroll
                for (int r = 0; r < 4; ++r) {
                    const int row = g * 4 + r;
                    const f16 hv = (r < 2) ? p01[r & 1] : p23[r & 1];
                    Pw[row * 64 + ((nb * 16 + c_) ^ ((row & 7) << 3))] = hv;
                }
            }

            // ---- stage V(t+1) into other buffer (hides under P/PV) ----
            if (more) STAGE_V(pb ^ 1);

            // ---- PV: A = P, B = Vt[pb] ----
#pragma unroll
            for (int ks = 0; ks < 2; ++ks) {
                f16x8 pa = *(const f16x8*)&Pw[c_ * 64 + ((ks * 32 + g * 8) ^ ((c_ & 7) << 3))];
                __builtin_amdgcn_s_setprio(1);
#pragma unroll
                for (int dblk = 0; dblk < 8; ++dblk) {
                    const int d  = dblk * 16 + c_;
                    f16x8 vb = *(const f16x8*)&Vt[pb][d * 64 + ((ks * 32 + g * 8) ^ SWV(d))];
                    Oa[dblk] = __builtin_amdgcn_mfma_f32_16x16x32_f16(pa, vb, Oa[dblk], 0, 0, 0);
                }
                __builtin_amdgcn_s_setprio(0);
            }

            // ---- issue global loads for tile t+2 (regs now free) ----
            if (t + 2 < t1) LOADT(t + 2);
            if (more) __syncthreads();
        }
    }

    // ---- reduce deferred l across the 16 key-lanes ----
    float lrun[4];
#pragma unroll
    for (int r = 0; r < 4; ++r) {
        float v = lpart[r];
        v += __shfl_xor(v, 1);
        v += __shfl_xor(v, 2);
        v += __shfl_xor(v, 4);
        v += __shfl_xor(v, 8);
        lrun[r] = v;
    }

    // ---- epilogue ----
    if (NS == 1) {
#pragma unroll
        for (int r = 0; r < 4; ++r) {
            const int qrow = qrow0 + g * 4 + r;
            float* dst = Og + (size_t)(bb * SS + qrow) * DD + c_;
            const float inv = 1.0f / lrun[r];
#pragma unroll
            for (int dblk = 0; dblk < 8; ++dblk)
                dst[dblk * 16] = Oa[dblk][r] * inv;
        }
    } else {
        // unnormalized f16 partial + (m, l)
        f16*    od  = Opf + (size_t)sg * SEG;
        float2* mld = mlb + (size_t)sg * BB * SS;
#pragma unroll
        for (int r = 0; r < 4; ++r) {
            const int qrow = qrow0 + g * 4 + r;
            f16* dst = od + (size_t)(bb * SS + qrow) * DD + c_;
#pragma unroll
            for (int dblk = 0; dblk < 8; ++dblk)
                dst[dblk * 16] = (f16)Oa[dblk][r];
            if (c_ == 0) mld[bb * SS + qrow] = make_float2(mrun[r], lrun[r]);
        }
    }
}

// ---------------------------------------------------------------------------
// Merge NS KV-split f16 partials: out = (sum Oi*ei) / (sum li*ei)
// Each thread handles 8 contiguous d-elements of one row.
// ---------------------------------------------------------------------------
template <int NS>
__global__ __launch_bounds__(256)
void merge_kernel(float* __restrict__ out, const f16* __restrict__ Opf,
                  const float2* __restrict__ mlb)
{
    const int idx = blockIdx.x * 256 + threadIdx.x;  // 8-elem units
    const int row = idx >> 4;                        // 16 units per row
    float2 ml[NS];
#pragma unroll
    for (int i = 0; i < NS; ++i) ml[i] = mlb[(size_t)i * BB * SS + row];
    float mm = ml[0].x;
#pragma unroll
    for (int i = 1; i < NS; ++i) mm = fmaxf(mm, ml[i].x);
    float e[NS], den = 0.f;
#pragma unroll
    for (int i = 0; i < NS; ++i) {
        e[i] = fast_exp2(ml[i].x - mm);
        den += ml[i].y * e[i];
    }
    const float inv = 1.0f / den;

    float acc[8] = {0.f, 0.f, 0.f, 0.f, 0.f, 0.f, 0.f, 0.f};
#pragma unroll
    for (int i = 0; i < NS; ++i) {
        f16x8 v = *(const f16x8*)(Opf + (size_t)i * SEG + (size_t)idx * 8);
#pragma unroll
        for (int j = 0; j < 8; ++j) acc[j] += (float)v[j] * e[i];
    }
    float4 o0, o1;
    o0.x = acc[0] * inv; o0.y = acc[1] * inv; o0.z = acc[2] * inv; o0.w = acc[3] * inv;
    o1.x = acc[4] * inv; o1.y = acc[5] * inv; o1.z = acc[6] * inv; o1.w = acc[7] * inv;
    float4* dst = (float4*)(out + (size_t)idx * 8);
    dst[0] = o0;
    dst[1] = o1;
}

extern "C" void kernel_launch(void* const* d_in, const int* in_sizes, int n_in,
                              void* d_out, int out_size, void* d_ws, size_t ws_size,
                              hipStream_t stream)
{
    const float* Q = (const float*)d_in[0];
    const float* K = (const float*)d_in[1];
    const float* V = (const float*)d_in[2];
    float* out = (float*)d_out;

    const size_t OPB = SEG * sizeof(f16);                 // 4 MB per segment
    const size_t MLB = (size_t)BB * SS * sizeof(float2);  // 128 KB per segment
    const int mergeGrid = (int)(SEG / 8 / 256);           // 1024

    const size_t need4 = 4 * OPB + 4 * MLB;

    if (ws_size >= need4) {
        f16*    Opf = (f16*)d_ws;
        float2* mlb = (float2*)((char*)d_ws + 4 * OPB);
        hipLaunchKernelGGL((attn_fwd<4>), dim3(8 * 32 * 4), dim3(256), 0, stream,
                           Q, K, V, out, Opf, mlb);
        hipLaunchKernelGGL((merge_kernel<4>), dim3(mergeGrid), dim3(256), 0, stream,
                           out, Opf, mlb);
    } else {
        hipLaunchKernelGGL((attn_fwd<1>), dim3(8 * 32), dim3(256), 0, stream,
                           Q, K, V, out, (f16*)nullptr, (float2*)nullptr);
    }
}